// Round 20
// baseline (195.736 us; speedup 1.0000x reference)
//
#include <hip/hip_runtime.h>
#include <stdint.h>

#define B_ 64
#define D_ 1024
#define O_ 512
#define N_ 128
// rows = O_*D_ = 524288 weight bitstream rows, each of length N_=128

__device__ __forceinline__ uint32_t rotl32(uint32_t x, uint32_t d) {
  return __builtin_amdgcn_alignbit(x, x, 32u - d);
}

// Threefry-2x32, 20 rounds, key fixed to jax.random.key(42) -> (0, 42).
__device__ __forceinline__ void threefry2x32(uint32_t c0, uint32_t c1,
                                             uint32_t& r0, uint32_t& r1) {
  const uint32_t ks0 = 0u;
  const uint32_t ks1 = 42u;
  const uint32_t ks2 = 0u ^ 42u ^ 0x1BD11BDAu;
  uint32_t x0 = c0 + ks0;
  uint32_t x1 = c1 + ks1;
#define RND(R) { x0 += x1; x1 = rotl32(x1, R); x1 ^= x0; }
  RND(13) RND(15) RND(26) RND(6)
  x0 += ks1; x1 += ks2 + 1u;
  RND(17) RND(29) RND(16) RND(24)
  x0 += ks2; x1 += ks0 + 2u;
  RND(13) RND(15) RND(26) RND(6)
  x0 += ks0; x1 += ks1 + 3u;
  RND(17) RND(29) RND(16) RND(24)
  x0 += ks1; x1 += ks2 + 4u;
  RND(13) RND(15) RND(26) RND(6)
  x0 += ks2; x1 += ks0 + 5u;
#undef RND
  r0 = x0; r1 = x1;
}

__device__ __forceinline__ uint32_t rand_bits(uint32_t i) {
  uint32_t a, b;
  threefry2x32(0u, i, a, b);
  return a ^ b;
}

// Verified single-row search (byte-identical asm to R14/R15/R18 green runs).
__device__ __forceinline__ void row_select(uint32_t k0, uint32_t k1, int n,
                                           uint64_t& m0, uint64_t& m1) {
#define PROBE_UPDATE_EXIT                                          \
      "v_cmp_lt_u32 %[q0], %[k0], %[m]\n\t"                        \
      "v_cmp_lt_u32 %[q1], %[k1], %[m]\n\t"                        \
      "s_bcnt1_i32_b64 %[c], %[q0]\n\t"                            \
      "s_bcnt1_i32_b64 %[c2], %[q1]\n\t"                           \
      "s_add_i32 %[c], %[c], %[c2]\n\t"                            \
      "s_cmp_ge_i32 %[c], %[ns]\n\t"                               \
      "s_cselect_b32 %[hi], %[m], %[hi]\n\t"                       \
      "s_cselect_b32 %[lo], %[lo], %[m]\n\t"                       \
      "s_cmp_eq_i32 %[c], %[ns]\n\t"                               \
      "s_cbranch_scc1 Ldone%=\n\t"
#define INTERP_MID                                                 \
      "s_sub_i32 %[d], %[ns], %[c]\n\t"                            \
      "s_lshl_b32 %[d], %[d], 23\n\t"                              \
      "s_add_u32 %[m], %[m], %[d]\n\t"                             \
      "s_add_u32 %[t1], %[lo], 1\n\t"                              \
      "s_add_u32 %[t2], %[hi], -1\n\t"                             \
      "s_min_u32 %[m], %[m], %[t2]\n\t"                            \
      "s_max_u32 %[m], %[m], %[t1]\n\t"
  if (n <= 0) {
    m0 = 0ull; m1 = 0ull;
  } else if (n >= 128) {
    m0 = ~0ull; m1 = ~0ull;
  } else {
    uint64_t q0, q1;
    uint32_t lo, hi, m, c, c2, ns, d, t1, t2;
    asm volatile(
      "v_readfirstlane_b32 %[ns], %[nv]\n\t"
      "s_mov_b32 %[lo], 0\n\t"
      "s_mov_b32 %[hi], 0x40000000\n\t"
      "s_lshl_b32 %[m], %[ns], 23\n\t"
      PROBE_UPDATE_EXIT
      INTERP_MID
      PROBE_UPDATE_EXIT
      INTERP_MID
      PROBE_UPDATE_EXIT
      INTERP_MID
      PROBE_UPDATE_EXIT
      "Lbs%=:\n\t"
      "s_add_u32 %[m], %[lo], %[hi]\n\t"
      "s_lshr_b32 %[m], %[m], 1\n\t"
      "s_add_u32 %[t1], %[lo], 1\n\t"
      "s_max_u32 %[m], %[m], %[t1]\n\t"
      "v_cmp_lt_u32 %[q0], %[k0], %[m]\n\t"
      "v_cmp_lt_u32 %[q1], %[k1], %[m]\n\t"
      "s_bcnt1_i32_b64 %[c], %[q0]\n\t"
      "s_bcnt1_i32_b64 %[c2], %[q1]\n\t"
      "s_add_i32 %[c], %[c], %[c2]\n\t"
      "s_cmp_ge_i32 %[c], %[ns]\n\t"
      "s_cselect_b32 %[hi], %[m], %[hi]\n\t"
      "s_cselect_b32 %[lo], %[lo], %[m]\n\t"
      "s_cmp_lg_i32 %[c], %[ns]\n\t"
      "s_cbranch_scc1 Lbs%=\n\t"
      "Ldone%=:\n\t"
      : [q0] "=&s"(q0), [q1] "=&s"(q1), [lo] "=&s"(lo), [hi] "=&s"(hi),
        [m] "=&s"(m), [c] "=&s"(c), [c2] "=&s"(c2), [ns] "=&s"(ns),
        [d] "=&s"(d), [t1] "=&s"(t1), [t2] "=&s"(t2)
      : [k0] "v"(k0), [k1] "v"(k1), [nv] "v"(n)
      : "scc");
    m0 = q0; m1 = q1;
  }
#undef PROBE_UPDATE_EXIT
#undef INTERP_MID
}

// K1: pack input bits along d.
__global__ void pack_x(const int* __restrict__ x, uint32_t* __restrict__ xp) {
  const int t   = threadIdx.x;
  const int idx = blockIdx.x;
  const int b   = idx >> 5;
  const int g   = (idx >> 2) & 7;
  const int e   = idx & 3;
  const int* src = x + ((b * D_) + (g * 128 + e * 32)) * N_ + t;
  uint32_t w = 0;
#pragma unroll
  for (int j = 0; j < 32; ++j)
    w |= (uint32_t)(src[j * N_] & 1) << j;
  xp[(((b * 8) + g) * N_ + t) * 4 + e] = w;
}

// K2 (FUSED gen_weights + pack_w), with PAIR-LOCKSTEP selection:
// one asm block advances TWO rows per level (4 v_cmp issued back-to-back
// share one VALU->SALU round trip; crossings/row ~5.5 -> ~3.2).
// Freeze rule: when a row's count==n at mid m, set (lo,hi) <- (m-1, m).
// Then every later level both mid formulas re-resolve to exactly m:
//   bisect: max((2m-1)>>1, lo+1) = max(m-1, m) = m;
//   interp: d = n-c = 0, clamp to [lo+1, hi-1] -> min(m,m-1)=m-1, max(..,m)=m.
// So frozen rows re-yield count==n each level (stable), the exit test
// "both rows count==n this level" is monotone, ballots at exit are each
// row's correct mask, and termination is bounded (non-frozen width halves;
// width-1 forces count==n — R9-verified theorem).  Non-frozen rows execute
// the byte-identical verified probe sequence.  Pairs with an n-edge row
// (~1.6%) take the verified single-row path for both rows.
__global__ void gen_weights(const float* __restrict__ kern, uint32_t* __restrict__ wp) {
  __shared__ uint32_t lds_m[32][4];
  __shared__ uint32_t lds_p[2][128];

  const int lane = threadIdx.x & 63;
  const int wave = threadIdx.x >> 6;
  const int row0 = blockIdx.x * 32 + wave * 8;
  const uint32_t lane2 = (uint32_t)lane + 64u;
  const uint32_t KMASK = 0xFFFFFF80u;
  const uint32_t base_i = (uint32_t)row0 * 128u + (uint32_t)lane;

  // all 8 rows' keys + n upfront (kept from R18: 8-way ILP threefry burst)
  uint32_t k0a[8], k1a[8];
  int na[8];
#pragma unroll
  for (int rr = 0; rr < 8; ++rr) {
    const uint32_t i0 = base_i + (uint32_t)(rr * 128);
    k0a[rr] = ((rand_bits(i0) >> 2) & KMASK) | (uint32_t)lane;
    k1a[rr] = ((rand_bits(i0 + 64u) >> 2) & KMASK) | lane2;
    float p = fminf(fmaxf(kern[row0 + rr], 0.0f), 1.0f);
    na[rr] = (int)rintf(p * 128.0f);      // RNE, matches jnp.round; uniform
  }

// ---- pair-lockstep macros (R = "A" / "B" literal) ----
#define CMP4                                                       \
      "v_cmp_lt_u32 %[q0A], %[k0A], %[mA]\n\t"                     \
      "v_cmp_lt_u32 %[q1A], %[k1A], %[mA]\n\t"                     \
      "v_cmp_lt_u32 %[q0B], %[k0B], %[mB]\n\t"                     \
      "v_cmp_lt_u32 %[q1B], %[k1B], %[mB]\n\t"
#define ROWUPD(R)                                                  \
      "s_bcnt1_i32_b64 %[cc], %[q0" R "]\n\t"                      \
      "s_bcnt1_i32_b64 %[c2], %[q1" R "]\n\t"                      \
      "s_add_i32 %[cc], %[cc], %[c2]\n\t"                          \
      "s_sub_i32 %[d" R "], %[ns" R "], %[cc]\n\t"                 \
      "s_cmp_ge_i32 %[cc], %[ns" R "]\n\t"                         \
      "s_cselect_b32 %[hi" R "], %[m" R "], %[hi" R "]\n\t"        \
      "s_cselect_b32 %[lo" R "], %[lo" R "], %[m" R "]\n\t"        \
      "s_sub_u32 %[t2], %[m" R "], 1\n\t"                          \
      "s_cmp_eq_i32 %[cc], %[ns" R "]\n\t"                         \
      "s_cselect_b32 %[lo" R "], %[t2], %[lo" R "]\n\t"            \
      "s_cselect_b32 %[f" R "], 1, 0\n\t"
#define MIDI(R)                                                    \
      "s_lshl_b32 %[t1], %[d" R "], 23\n\t"                        \
      "s_add_u32 %[m" R "], %[m" R "], %[t1]\n\t"                  \
      "s_add_u32 %[t1], %[lo" R "], 1\n\t"                         \
      "s_add_u32 %[t2], %[hi" R "], -1\n\t"                        \
      "s_min_u32 %[m" R "], %[m" R "], %[t2]\n\t"                  \
      "s_max_u32 %[m" R "], %[m" R "], %[t1]\n\t"
#define MIDB(R)                                                    \
      "s_add_u32 %[m" R "], %[lo" R "], %[hi" R "]\n\t"            \
      "s_lshr_b32 %[m" R "], %[m" R "], 1\n\t"                     \
      "s_add_u32 %[t1], %[lo" R "], 1\n\t"                         \
      "s_max_u32 %[m" R "], %[m" R "], %[t1]\n\t"
#define EXIT_FWD                                                   \
      "s_and_b32 %[t1], %[fA], %[fB]\n\t"                          \
      "s_cmp_eq_u32 %[t1], 1\n\t"                                  \
      "s_cbranch_scc1 Lpd%=\n\t"

#pragma unroll
  for (int pr = 0; pr < 4; ++pr) {
    const int rA = pr * 2, rB = pr * 2 + 1;
    const uint32_t k0A = k0a[rA], k1A = k1a[rA];
    const uint32_t k0B = k0a[rB], k1B = k1a[rB];
    const int nA = na[rA], nB = na[rB];

    uint64_t m0A, m1A, m0B, m1B;
    if (nA >= 1 && nA <= 127 && nB >= 1 && nB <= 127) {
      uint64_t q0A, q1A, q0B, q1B;
      uint32_t loA, hiA, loB, hiB, mA, mB, nsA, nsB, cc, c2, dA, dB, t1, t2, fA, fB;
      asm volatile(
        "v_readfirstlane_b32 %[nsA], %[nvA]\n\t"
        "v_readfirstlane_b32 %[nsB], %[nvB]\n\t"
        "s_mov_b32 %[loA], 0\n\t"
        "s_mov_b32 %[hiA], 0x40000000\n\t"
        "s_mov_b32 %[loB], 0\n\t"
        "s_mov_b32 %[hiB], 0x40000000\n\t"
        "s_lshl_b32 %[mA], %[nsA], 23\n\t"
        "s_lshl_b32 %[mB], %[nsB], 23\n\t"
        // level 1 (interp seed)
        CMP4 ROWUPD("A") ROWUPD("B") EXIT_FWD
        // levels 2-4 (interp correction)
        MIDI("A") MIDI("B") CMP4 ROWUPD("A") ROWUPD("B") EXIT_FWD
        MIDI("A") MIDI("B") CMP4 ROWUPD("A") ROWUPD("B") EXIT_FWD
        MIDI("A") MIDI("B") CMP4 ROWUPD("A") ROWUPD("B") EXIT_FWD
        // bisection loop (width-1 theorem forces each row's exit <= 30 lvls)
        "Lpb%=:\n\t"
        MIDB("A") MIDB("B") CMP4 ROWUPD("A") ROWUPD("B")
        "s_and_b32 %[t1], %[fA], %[fB]\n\t"
        "s_cmp_eq_u32 %[t1], 1\n\t"
        "s_cbranch_scc0 Lpb%=\n\t"
        "Lpd%=:\n\t"
        : [q0A] "=&s"(q0A), [q1A] "=&s"(q1A), [q0B] "=&s"(q0B), [q1B] "=&s"(q1B),
          [loA] "=&s"(loA), [hiA] "=&s"(hiA), [loB] "=&s"(loB), [hiB] "=&s"(hiB),
          [mA] "=&s"(mA), [mB] "=&s"(mB), [nsA] "=&s"(nsA), [nsB] "=&s"(nsB),
          [cc] "=&s"(cc), [c2] "=&s"(c2), [dA] "=&s"(dA), [dB] "=&s"(dB),
          [t1] "=&s"(t1), [t2] "=&s"(t2), [fA] "=&s"(fA), [fB] "=&s"(fB)
        : [k0A] "v"(k0A), [k1A] "v"(k1A), [k0B] "v"(k0B), [k1B] "v"(k1B),
          [nvA] "v"(nA), [nvB] "v"(nB)
        : "scc");
      m0A = q0A; m1A = q1A; m0B = q0B; m1B = q1B;
    } else {
      row_select(k0A, k1A, nA, m0A, m1A);
      row_select(k0B, k1B, nB, m0B, m1B);
    }

    if (lane == 0) {
      const int ra = wave * 8 + rA;
      lds_m[ra][0] = (uint32_t)m0A;
      lds_m[ra][1] = (uint32_t)(m0A >> 32);
      lds_m[ra][2] = (uint32_t)m1A;
      lds_m[ra][3] = (uint32_t)(m1A >> 32);
      lds_m[ra + 1][0] = (uint32_t)m0B;
      lds_m[ra + 1][1] = (uint32_t)(m0B >> 32);
      lds_m[ra + 1][2] = (uint32_t)m1B;
      lds_m[ra + 1][3] = (uint32_t)(m1B >> 32);
    }
  }
#undef CMP4
#undef ROWUPD
#undef MIDI
#undef MIDB
#undef EXIT_FWD

  __syncthreads();
  // bit-transpose: thread (p, t) gathers bit t of rows p*16..p*16+15
  const int p  = threadIdx.x >> 7;
  const int t  = threadIdx.x & 127;
  const int wi = t >> 5, bit = t & 31;
  uint32_t part = 0;
#pragma unroll
  for (int j = 0; j < 16; ++j)
    part |= ((lds_m[p * 16 + j][wi] >> bit) & 1u) << (p * 16 + j);
  lds_p[p][t] = part;
  __syncthreads();
  if (threadIdx.x < 128) {
    const int o = blockIdx.x >> 5;
    const int g = (blockIdx.x >> 2) & 7;
    const int e = blockIdx.x & 3;
    wp[(size_t)(((o * 8 + g) * 4 + e) * 128) + t] = lds_p[0][t] | lds_p[1][t];
  }
}

// K3: out[b][o][t] = popc-dot over 1024 d's (32 words) / 128.  Exact ints.
__global__ void popc_gemm(const uint32_t* __restrict__ wp, const uint4* __restrict__ xp,
                          float* __restrict__ out) {
  const int t     = threadIdx.x & 127;
  const int oi    = threadIdx.x >> 7;
  const int opair = blockIdx.x >> 3;
  const int btile = blockIdx.x & 7;
  const int o     = opair * 2 + oi;

  uint4 w[8];
#pragma unroll
  for (int g = 0; g < 8; ++g) {
    const uint32_t* wpw = wp + (size_t)((o * 8 + g) * 4) * 128 + t;
    w[g].x = wpw[0];
    w[g].y = wpw[128];
    w[g].z = wpw[256];
    w[g].w = wpw[384];
  }

#pragma unroll
  for (int ib = 0; ib < 8; ++ib) {
    const int b = btile * 8 + ib;
    uint32_t acc = 0;
#pragma unroll
    for (int g = 0; g < 8; ++g) {
      const uint4 xv = xp[(b * 8 + g) * N_ + t];
      acc += __popc(w[g].x & xv.x);
      acc += __popc(w[g].y & xv.y);
      acc += __popc(w[g].z & xv.z);
      acc += __popc(w[g].w & xv.w);
    }
    out[((size_t)(b * O_) + o) * N_ + t] = (float)acc * (1.0f / 128.0f);
  }
}

extern "C" void kernel_launch(void* const* d_in, const int* in_sizes, int n_in,
                              void* d_out, int out_size, void* d_ws, size_t ws_size,
                              hipStream_t stream) {
  const int*   x    = (const int*)d_in[0];     // (64,1024,128) int32 0/1
  const float* kern = (const float*)d_in[1];   // (512,1024) float32
  float*       out  = (float*)d_out;           // (64,512,128) float32

  char* ws = (char*)d_ws;
  uint32_t* xp = (uint32_t*)ws;                    // 1 MB
  uint32_t* wp = (uint32_t*)(ws + (1u << 20));     // 8 MB

  hipLaunchKernelGGL(pack_x,      dim3(2048),  dim3(128), 0, stream, x, xp);
  hipLaunchKernelGGL(gen_weights, dim3(16384), dim3(256), 0, stream, kern, wp);
  hipLaunchKernelGGL(popc_gemm,   dim3(2048),  dim3(256), 0, stream,
                     wp, (const uint4*)xp, out);
}